// Round 4
// baseline (819.097 us; speedup 1.0000x reference)
//
#include <hip/hip_runtime.h>
#include <hip/hip_bf16.h>
#include <cmath>

// Problem: CPL_MoE  B=32, L=64, H=1024, E=8, K=2, V=12000, OUT=16
#define B_   32
#define L_   64
#define H_   1024
#define E_   8
#define V_   12000
#define OUT_ 16
#define HID_ 512

#define BN  96   // v-tile per block (125 tiles * 96 = 12000 exactly)
#define BK  64   // k-tile
#define LDK 72   // padded LDS row stride (fallback kernel)
#define NVT (V_ / BN)   // 125

#define COMP_OFF 512                      // d_out: [0,512) gauss_param
#define LOSS_OFF (512 + B_ * L_ * V_)     // last element: moe_loss

using f32x4  = __attribute__((ext_vector_type(4))) float;
using bf16x8 = __attribute__((ext_vector_type(8))) short;
using s16x4  = __attribute__((ext_vector_type(4))) short;

__device__ __forceinline__ short f2bf(float f) {
  unsigned u = __builtin_bit_cast(unsigned, f);
  u = (u + 0x7FFFu + ((u >> 16) & 1u)) >> 16;   // round-to-nearest-even
  return (short)u;
}

// async global->LDS DMA, 16 B per lane. dst must be (wave-uniform base + lane*16).
typedef __attribute__((address_space(1))) void gvoid_t;
typedef __attribute__((address_space(3))) void lvoid_t;
#define GLOAD16(g, l) __builtin_amdgcn_global_load_lds((gvoid_t*)(g), (lvoid_t*)(l), 16, 0, 0)

// ---------------------------------------------------------------------------
// Kernel: f32 -> bf16 bulk convert (used for h only: 4 MB, ~3 us).
// ---------------------------------------------------------------------------
__global__ __launch_bounds__(256) void k_conv(const float* __restrict__ src,
                                              short* __restrict__ dst, int n8) {
  size_t i = (size_t)blockIdx.x * 256 + threadIdx.x;
  const size_t stride = (size_t)gridDim.x * 256;
  for (; i < (size_t)n8; i += stride) {
    const f32x4 a = ((const f32x4*)src)[2 * i];
    const f32x4 b = ((const f32x4*)src)[2 * i + 1];
    bf16x8 o;
    o[0] = f2bf(a[0]); o[1] = f2bf(a[1]); o[2] = f2bf(a[2]); o[3] = f2bf(a[3]);
    o[4] = f2bf(b[0]); o[5] = f2bf(b[1]); o[6] = f2bf(b[2]); o[7] = f2bf(b[3]);
    ((bf16x8*)dst)[i] = o;
  }
}

// ---------------------------------------------------------------------------
// Kernel 1: gating + fused gauss_param. One block per batch row.
// ---------------------------------------------------------------------------
__global__ __launch_bounds__(256) void k_gate(
    const float* __restrict__ q,  const float* __restrict__ w1,
    const float* __restrict__ b1, const float* __restrict__ w2,
    const float* __restrict__ b2, const float* __restrict__ h,
    const float* __restrict__ gw, const float* __restrict__ gb,
    float* __restrict__ gates,    float* __restrict__ egate,
    int* __restrict__ eidx,       float* __restrict__ out) {
  __shared__ __align__(16) float qs[H_];
  __shared__ __align__(16) float hid[HID_];
  __shared__ __align__(16) float red[256][8];
  __shared__ float sg[2];
  __shared__ int   se[2];
  const int t = threadIdx.x;
  const int b = blockIdx.x;

  ((f32x4*)qs)[t] = ((const f32x4*)(q + (size_t)b * H_))[t];
  __syncthreads();

  {
    const int jq = t & 127, ih = t >> 7;
    f32x4 acc = {0.f, 0.f, 0.f, 0.f};
    const float* wp = w1 + (size_t)(ih * 512) * HID_ + 4 * jq;
    for (int i = 0; i < 512; ++i) {
      acc += qs[ih * 512 + i] * *(const f32x4*)(wp + (size_t)i * HID_);
    }
    *(f32x4*)&red[t][0] = acc;
  }
  __syncthreads();
  if (t < 128) {
    f32x4 a = *(f32x4*)&red[t][0];
    a += *(f32x4*)&red[t + 128][0];
    a += *(const f32x4*)(b1 + 4 * t);
    f32x4 r;
    #pragma unroll
    for (int c = 0; c < 4; ++c) r[c] = fmaxf(a[c], 0.f);
    *(f32x4*)&hid[4 * t] = r;
  }
  __syncthreads();

  {
    const float h0 = hid[t], h1 = hid[t + 256];
    const float* w2a = w2 + (size_t)t * E_;
    const float* w2b = w2 + (size_t)(t + 256) * E_;
    #pragma unroll
    for (int e = 0; e < 8; ++e) red[t][e] = h0 * w2a[e] + h1 * w2b[e];
  }
  __syncthreads();
  for (int s = 128; s > 0; s >>= 1) {
    if (t < s) {
      #pragma unroll
      for (int e = 0; e < 8; ++e) red[t][e] += red[t + s][e];
    }
    __syncthreads();
  }

  if (t == 0) {
    float lg[8];
    #pragma unroll
    for (int e = 0; e < 8; ++e) lg[e] = red[0][e] + b2[e];
    int e1 = 0;
    #pragma unroll
    for (int e = 1; e < 8; ++e) if (lg[e] > lg[e1]) e1 = e;     // lowest idx wins ties
    int e2 = (e1 == 0) ? 1 : 0;
    #pragma unroll
    for (int e = 0; e < 8; ++e) if (e != e1 && lg[e] > lg[e2]) e2 = e;
    const float x2 = expf(lg[e2] - lg[e1]);
    const float g1 = 1.f / (1.f + x2);
    const float g2 = x2 / (1.f + x2);
    #pragma unroll
    for (int e = 0; e < 8; ++e)
      gates[b * E_ + e] = (e == e1) ? g1 : (e == e2) ? g2 : 0.f;
    egate[2 * b] = g1; egate[2 * b + 1] = g2;
    eidx[2 * b]  = e1; eidx[2 * b + 1]  = e2;
    sg[0] = g1; sg[1] = g2; se[0] = e1; se[1] = e2;
  }
  __syncthreads();

  {
    const float gg1 = sg[0], gg2 = sg[1];
    const int ee1 = se[0], ee2 = se[1];
    const int o = t >> 4, sub = t & 15;
    const float* hl = h  + ((size_t)(b * L_ + (L_ - 1))) * H_ + sub * 64;
    const float* wa = gw + ((size_t)(ee1 * OUT_ + o)) * H_ + sub * 64;
    const float* wb = gw + ((size_t)(ee2 * OUT_ + o)) * H_ + sub * 64;
    float p = 0.f;
    #pragma unroll 4
    for (int i = 0; i < 64; i += 4) {
      const f32x4 hv = *(const f32x4*)(hl + i);
      const f32x4 va = *(const f32x4*)(wa + i);
      const f32x4 vb = *(const f32x4*)(wb + i);
      const f32x4 w  = gg1 * va + gg2 * vb;
      p += hv[0] * w[0] + hv[1] * w[1] + hv[2] * w[2] + hv[3] * w[3];
    }
    float* red1 = &red[0][0];
    red1[t] = p;
    __syncthreads();
    if (t < 16) {
      float s = gg1 * gb[ee1 * OUT_ + t] + gg2 * gb[ee2 * OUT_ + t];
      #pragma unroll
      for (int k2 = 0; k2 < 16; ++k2) s += red1[t * 16 + k2];
      out[b * OUT_ + t] = 1.f / (1.f + expf(-s));
    }
  }
}

// ---------------------------------------------------------------------------
// Kernel: moe_loss only.
// ---------------------------------------------------------------------------
__global__ __launch_bounds__(64) void k_loss(const float* __restrict__ gates,
                                             float* __restrict__ out) {
  __shared__ float imp[8];
  const int t = threadIdx.x;
  if (t < 8) {
    float s = 0.f;
    for (int b = 0; b < B_; ++b) s += gates[b * E_ + t];
    imp[t] = s;
  }
  __syncthreads();
  if (t == 0) {
    float m = 0.f;
    #pragma unroll
    for (int e = 0; e < 8; ++e) m += imp[e];
    m *= 0.125f;
    float var = 0.f;
    #pragma unroll
    for (int e = 0; e < 8; ++e) { const float d = imp[e] - m; var += d * d; }
    var *= (1.f / 7.f);
    out[LOSS_OFF] = sqrtf(var) / (m + 1e-10f) * 0.1f;
  }
}

// ---------------------------------------------------------------------------
// Kernel 3 (fast): comp GEMM, fused f32->bf16 mix, XCD-confined vt mapping,
// and a COUNTED-VMCNT software pipeline (no __syncthreads in the K-loop):
//   - B regs prefetched 2 tiles ahead (two named sets, full unroll -> static
//     indexing). Compiler's data-dep wait at WRITEB becomes vmcnt(14):
//     14 newer vmem ops (2 A-GLOADs + 12 B loads) stay in flight across
//     both barriers.
//   - A staged via global_load_lds 1 tile ahead, double-buffered; its
//     completion is guarded by an explicit vmcnt(12) (retires the 2 oldest
//     = previous iteration's A GLOADs) before the ds_reads.
//   - barrier1 = lgkmcnt(0)+s_barrier (publish ds_writes); barrier2 = raw
//     s_barrier (ds_reads already retired by MFMA data deps). Nothing
//     drains vmcnt to 0 inside the loop.
// Hazards: Bs WAR -> barrier2; As[next] GLOAD targets buffer last read
// before previous barrier2; A-before-B issue order pinned by "" memory
// fences so in-order vmcnt retirement makes the counts exact.
// ---------------------------------------------------------------------------
__global__ __launch_bounds__(256) void k_comp_fast(
    const short* __restrict__ hbf, const float* __restrict__ cw,
    const float* __restrict__ cb,  const float* __restrict__ egate,
    const int* __restrict__ eidx,  float* __restrict__ out) {
  __shared__ __align__(16) short As[2][64 * 64];   // 2 x 8 KB (double-buffered)
  __shared__ __align__(16) short Bs[96 * 64];      // 12 KB (mixed weights)
  const int t  = threadIdx.x;
  const int id  = blockIdx.x;
  const int xcd = id & 7;
  const int pos = id >> 3;          // 0..511
  const int b   = pos & 31;
  const int g   = pos >> 5;         // 0..15
  const int vt  = g * 8 + xcd;      // 0..127
  if (vt >= NVT) return;            // 125 valid tiles; 96 idle blocks exit
  const int e1 = eidx[2 * b], e2 = eidx[2 * b + 1];
  const float g1 = egate[2 * b], g2 = egate[2 * b + 1];

  // --- A staging: GLOAD16, linear LDS dest, inverse-swizzled global source ---
  const int srow = t >> 3, schunk = t & 7;
  const unsigned soff = (unsigned)((schunk << 4) ^ ((srow & 7) << 4));
  const char* sAk = (const char*)hbf + ((size_t)b * 64 + srow) * 2048 + soff;

  // --- B staging: 3 passes x 32 rows; row = p*32 + srow, cols schunk*8..+8 ---
  const float* wB1 = cw + ((size_t)e1 * V_ + (size_t)vt * BN + srow) * H_ + schunk * 8;
  const float* wB2 = cw + ((size_t)e2 * V_ + (size_t)vt * BN + srow) * H_ + schunk * 8;
  short* dBp = Bs + srow * 64 + ((schunk ^ (srow & 7)) << 3);   // swizzled write base

  // two prefetch register sets (indices static after full unroll)
  f32x4 pa[2][3][2], pb[2][3][2];

#define LOADB(S, koff)                                                       \
  do {                                                                       \
    _Pragma("unroll")                                                        \
    for (int p = 0; p < 3; ++p) {                                            \
      pa[S][p][0] = *(const f32x4*)(wB1 + (size_t)p * 32 * H_ + (koff));     \
      pa[S][p][1] = *(const f32x4*)(wB1 + (size_t)p * 32 * H_ + (koff) + 4); \
      pb[S][p][0] = *(const f32x4*)(wB2 + (size_t)p * 32 * H_ + (koff));     \
      pb[S][p][1] = *(const f32x4*)(wB2 + (size_t)p * 32 * H_ + (koff) + 4); \
    }                                                                        \
  } while (0)

#define WRITEB(S)                                                            \
  do {                                                                       \
    _Pragma("unroll")                                                        \
    for (int p = 0; p < 3; ++p) {                                            \
      const f32x4 m0 = g1 * pa[S][p][0] + g2 * pb[S][p][0];                  \
      const f32x4 m1 = g1 * pa[S][p][1] + g2 * pb[S][p][1];                  \
      bf16x8 o;                                                              \
      o[0] = f2bf(m0[0]); o[1] = f2bf(m0[1]);                                \
      o[2] = f2bf(m0[2]); o[3] = f2bf(m0[3]);                                \
      o[4] = f2bf(m1[0]); o[5] = f2bf(m1[1]);                                \
      o[6] = f2bf(m1[2]); o[7] = f2bf(m1[3]);                                \
      *(bf16x8*)(dBp + p * 32 * 64) = o;                                     \
    }                                                                        \
  } while (0)

  // --- mfma geometry (wave: mh = M-half of 32 rows, ng*3..+3 = N-frags) ---
  const int lane = t & 63, wv = t >> 6;
  const int lr = lane & 15, quad = lane >> 4;
  const int mh = wv & 1, ng = wv >> 1;
  int offA[2][2], offB[3][2];   // [frag][ks] in shorts
  #pragma unroll
  for (int mf = 0; mf < 2; ++mf) {
    const int ra = mh * 32 + mf * 16 + lr;
    offA[mf][0] = ra * 64 + (((quad    ) ^ (ra & 7)) << 3);
    offA[mf][1] = ra * 64 + (((quad ^ 4) ^ (ra & 7)) << 3);
  }
  #pragma unroll
  for (int nn = 0; nn < 3; ++nn) {
    const int rb = (ng * 3 + nn) * 16 + lr;
    offB[nn][0] = rb * 64 + (((quad    ) ^ (rb & 7)) << 3);
    offB[nn][1] = rb * 64 + (((quad ^ 4) ^ (rb & 7)) << 3);
  }

  f32x4 acc[2][3];
  #pragma unroll
  for (int i = 0; i < 2; ++i)
    #pragma unroll
    for (int j = 0; j < 3; ++j) acc[i][j] = (f32x4){0.f, 0.f, 0.f, 0.f};

  // --- prologue: A tile0 in flight; B tiles 0 and 1 in regs-in-flight ---
  {
    char* dA0 = (char*)&As[0][0] + t * 16;
    GLOAD16(sAk,         dA0);
    GLOAD16(sAk + 65536, dA0 + 4096);
    sAk += 128;
  }
  asm volatile("" ::: "memory");
  LOADB(0, 0);
  asm volatile("" ::: "memory");
  LOADB(1, 64);
  asm volatile("" ::: "memory");

  #pragma unroll
  for (int u = 0; u < 16; ++u) {
    // phase 1: commit tile u's mixed B (compiler waits its regs: counted vmcnt)
    WRITEB(u & 1);
    asm volatile("s_waitcnt lgkmcnt(0)" ::: "memory");
    __builtin_amdgcn_s_barrier();

    // guard: previous iteration's A GLOAD (the 2 oldest in-flight ops)
    if (u == 0)       { asm volatile("" ::: "memory"); }
    else if (u < 15)  { asm volatile("s_waitcnt vmcnt(12)" ::: "memory"); }
    else              { asm volatile("s_waitcnt vmcnt(0)"  ::: "memory"); }

    // phase 2a: issue next loads (A first, then B — order pins vmcnt counting)
    if (u < 15) {
      char* dAn = (char*)&As[(u + 1) & 1][0] + t * 16;
      GLOAD16(sAk,         dAn);
      GLOAD16(sAk + 65536, dAn + 4096);
      sAk += 128;
      asm volatile("" ::: "memory");
    }
    if (u < 14) {
      LOADB((u & 1), (u + 2) * 64);
    }
    asm volatile("" ::: "memory");

    // phase 2b: compute tile u
    {
      const short* Asb = &As[u & 1][0];
      #pragma unroll
      for (int ks = 0; ks < 2; ++ks) {
        const bf16x8 a0 = *(const bf16x8*)(Asb + offA[0][ks]);
        const bf16x8 a1 = *(const bf16x8*)(Asb + offA[1][ks]);
        #pragma unroll
        for (int nn = 0; nn < 3; ++nn) {
          const bf16x8 wbm = *(const bf16x8*)(Bs + offB[nn][ks]);
          acc[0][nn] = __builtin_amdgcn_mfma_f32_16x16x32_bf16(a0, wbm, acc[0][nn], 0, 0, 0);
          acc[1][nn] = __builtin_amdgcn_mfma_f32_16x16x32_bf16(a1, wbm, acc[1][nn], 0, 0, 0);
        }
      }
    }
    asm volatile("" ::: "memory");
    __builtin_amdgcn_s_barrier();   // raw: Bs WAR only; vmcnt NOT drained
  }

  // epilogue: mixed bias (D layout: col=lane&15, row=quad*4+r)
  #pragma unroll
  for (int nn = 0; nn < 3; ++nn) {
    const int v = vt * BN + (ng * 3 + nn) * 16 + lr;
    const float bias = g1 * cb[e1 * V_ + v] + g2 * cb[e2 * V_ + v];
    #pragma unroll
    for (int mf = 0; mf < 2; ++mf) {
      const int lbase = mh * 32 + mf * 16 + quad * 4;
      float* op = out + COMP_OFF + ((size_t)(b * L_ + lbase)) * V_ + v;
      #pragma unroll
      for (int rr = 0; rr < 4; ++rr)
        op[(size_t)rr * V_] = acc[mf][nn][rr] + bias;
    }
  }
#undef LOADB
#undef WRITEB
}

// ---------------------------------------------------------------------------
// Kernel 3 (fallback, tiny-workspace path): f32 direct, mix-in-staging.
// ---------------------------------------------------------------------------
__global__ __launch_bounds__(256) void k_comp(
    const float* __restrict__ h,     const float* __restrict__ cw,
    const float* __restrict__ cbp,   const float* __restrict__ egate,
    const int* __restrict__ eidx,    float* __restrict__ out) {
  __shared__ __align__(16) short As[L_ * LDK];
  __shared__ __align__(16) short Bs[BN * LDK];
  const int t  = threadIdx.x;
  const int b  = blockIdx.x;
  const int vt = blockIdx.y;
  const int e1 = eidx[2 * b], e2 = eidx[2 * b + 1];
  const float g1 = egate[2 * b], g2 = egate[2 * b + 1];

  const float* hrow = h + ((size_t)b * L_ + (t >> 2)) * H_ + ((t & 3) * 16);
  const float* w1p  = cw + ((size_t)e1 * V_ + (size_t)vt * BN) * H_;
  const float* w2p  = cw + ((size_t)e2 * V_ + (size_t)vt * BN) * H_;

  f32x4 acc[6];
  #pragma unroll
  for (int i = 0; i < 6; ++i) acc[i] = (f32x4){0.f, 0.f, 0.f, 0.f};

  const int wv = t >> 6;
  const int lane = t & 63;
  const int lr = lane & 15, quad = lane >> 4;
  const short* Ap = As + (wv * 16 + lr) * LDK;
  const short* Bp = Bs + lr * LDK;

  const int wr = t >> 3;
  const int wc = (t & 7) * 8;

  for (int k0 = 0; k0 < H_; k0 += BK) {
    {
      const float* src = hrow + k0;
      short* dst = As + (t >> 2) * LDK + (t & 3) * 16;
      #pragma unroll
      for (int c = 0; c < 16; c += 4) {
        const f32x4 v = *(const f32x4*)(src + c);
        s16x4 sv;
        sv[0] = f2bf(v[0]); sv[1] = f2bf(v[1]);
        sv[2] = f2bf(v[2]); sv[3] = f2bf(v[3]);
        *(s16x4*)(dst + c) = sv;
      }
    }
    #pragma unroll
    for (int p = 0; p < 3; ++p) {
      const int r = p * 32 + wr;
      const float* s1 = w1p + (size_t)r * H_ + k0 + wc;
      const float* s2 = w2p + (size_t)r * H_ + k0 + wc;
      short* dst = Bs + r * LDK + wc;
      #pragma unroll
      for (int c = 0; c < 8; c += 4) {
        const f32x4 a  = *(const f32x4*)(s1 + c);
        const f32x4 bb = *(const f32x4*)(s2 + c);
        const f32x4 m  = g1 * a + g2 * bb;
        s16x4 sv;
        sv[0] = f2bf(m[0]); sv[1] = f2bf(m[1]);
        sv[2] = f2bf(m[2]); sv[3] = f2bf(m[3]);
        *(s16x4*)(dst + c) = sv;
      }
    }
    __syncthreads();

    #pragma unroll
    for (int ks = 0; ks < BK; ks += 32) {
      const bf16x8 af = *(const bf16x8*)(Ap + ks + quad * 8);
      #pragma unroll
      for (int n = 0; n < 6; ++n) {
        const bf16x8 bf = *(const bf16x8*)(Bp + n * 16 * LDK + ks + quad * 8);
        acc[n] = __builtin_amdgcn_mfma_f32_16x16x32_bf16(af, bf, acc[n], 0, 0, 0);
      }
    }
    __syncthreads();
  }

  #pragma unroll
  for (int n = 0; n < 6; ++n) {
    const int v = vt * BN + n * 16 + lr;
    const float bias = g1 * cbp[e1 * V_ + v] + g2 * cbp[e2 * V_ + v];
    #pragma unroll
    for (int r = 0; r < 4; ++r) {
      const int l = wv * 16 + quad * 4 + r;
      out[COMP_OFF + ((size_t)(b * L_ + l)) * V_ + v] = acc[n][r] + bias;
    }
  }
}

// ---------------------------------------------------------------------------
extern "C" void kernel_launch(void* const* d_in, const int* in_sizes, int n_in,
                              void* d_out, int out_size, void* d_ws, size_t ws_size,
                              hipStream_t stream) {
  const float* q   = (const float*)d_in[0];
  const float* h   = (const float*)d_in[1];
  const float* w1  = (const float*)d_in[2];
  const float* b1  = (const float*)d_in[3];
  const float* w2  = (const float*)d_in[4];
  const float* b2  = (const float*)d_in[5];
  const float* gw  = (const float*)d_in[6];
  const float* gb  = (const float*)d_in[7];
  const float* cw  = (const float*)d_in[8];
  const float* cbp = (const float*)d_in[9];
  float* out = (float*)d_out;

  // ws layout: [0,1024) gates/egate/eidx block; [4096, +4MB) h_bf16.
  float* F     = (float*)d_ws;
  float* gates = F;
  float* egate = F + 256;
  int*   eidx  = (int*)(F + 320);

  const size_t HBF_OFF = 4096;
  const size_t HBF_BYTES = (size_t)B_ * L_ * H_ * 2;   // 4,194,304
  const size_t WS_NEED = HBF_OFF + HBF_BYTES;

  k_gate<<<B_, 256, 0, stream>>>(q, w1, b1, w2, b2, h, gw, gb, gates, egate, eidx, out);
  k_loss<<<1, 64, 0, stream>>>(gates, out);

  if (ws_size >= WS_NEED) {
    short* hbf = (short*)((char*)d_ws + HBF_OFF);
    k_conv<<<256, 256, 0, stream>>>(h, hbf, (int)((size_t)B_ * L_ * H_ / 8));
    // 4096 blocks: 512 per XCD under id%8 round-robin; 96 exit early (vt>=125)
    k_comp_fast<<<4096, 256, 0, stream>>>(hbf, cw, cbp, egate, eidx, out);
  } else {
    k_comp<<<dim3(B_, V_ / BN), 256, 0, stream>>>(h, cw, cbp, egate, eidx, out);
  }
}

// Round 5
// 765.415 us; speedup vs baseline: 1.0701x; 1.0701x over previous
//
#include <hip/hip_runtime.h>
#include <hip/hip_bf16.h>
#include <cmath>

// Problem: CPL_MoE  B=32, L=64, H=1024, E=8, K=2, V=12000, OUT=16
#define B_   32
#define L_   64
#define H_   1024
#define E_   8
#define V_   12000
#define OUT_ 16
#define HID_ 512

#define BN  96   // v-tile per block (125 tiles * 96 = 12000 exactly)
#define BK  64   // k-tile
#define LDK 72   // padded LDS row stride (fallback kernel)
#define NVT (V_ / BN)   // 125

#define COMP_OFF 512                      // d_out: [0,512) gauss_param
#define LOSS_OFF (512 + B_ * L_ * V_)     // last element: moe_loss

using f32x4  = __attribute__((ext_vector_type(4))) float;
using bf16x8 = __attribute__((ext_vector_type(8))) short;
using s16x4  = __attribute__((ext_vector_type(4))) short;

__device__ __forceinline__ short f2bf(float f) {
  unsigned u = __builtin_bit_cast(unsigned, f);
  u = (u + 0x7FFFu + ((u >> 16) & 1u)) >> 16;   // round-to-nearest-even
  return (short)u;
}

// async global->LDS DMA, 16 B per lane. dst must be (wave-uniform base + lane*16).
typedef __attribute__((address_space(1))) void gvoid_t;
typedef __attribute__((address_space(3))) void lvoid_t;
#define GLOAD16(g, l) __builtin_amdgcn_global_load_lds((gvoid_t*)(g), (lvoid_t*)(l), 16, 0, 0)

// ---------------------------------------------------------------------------
// Kernel: f32 -> bf16 bulk convert (used for h only: 4 MB, ~3 us).
// ---------------------------------------------------------------------------
__global__ __launch_bounds__(256) void k_conv(const float* __restrict__ src,
                                              short* __restrict__ dst, int n8) {
  size_t i = (size_t)blockIdx.x * 256 + threadIdx.x;
  const size_t stride = (size_t)gridDim.x * 256;
  for (; i < (size_t)n8; i += stride) {
    const f32x4 a = ((const f32x4*)src)[2 * i];
    const f32x4 b = ((const f32x4*)src)[2 * i + 1];
    bf16x8 o;
    o[0] = f2bf(a[0]); o[1] = f2bf(a[1]); o[2] = f2bf(a[2]); o[3] = f2bf(a[3]);
    o[4] = f2bf(b[0]); o[5] = f2bf(b[1]); o[6] = f2bf(b[2]); o[7] = f2bf(b[3]);
    ((bf16x8*)dst)[i] = o;
  }
}

// ---------------------------------------------------------------------------
// Kernel 1: gating + fused gauss_param. One block per batch row.
// ---------------------------------------------------------------------------
__global__ __launch_bounds__(256) void k_gate(
    const float* __restrict__ q,  const float* __restrict__ w1,
    const float* __restrict__ b1, const float* __restrict__ w2,
    const float* __restrict__ b2, const float* __restrict__ h,
    const float* __restrict__ gw, const float* __restrict__ gb,
    float* __restrict__ gates,    float* __restrict__ egate,
    int* __restrict__ eidx,       float* __restrict__ out) {
  __shared__ __align__(16) float qs[H_];
  __shared__ __align__(16) float hid[HID_];
  __shared__ __align__(16) float red[256][8];
  __shared__ float sg[2];
  __shared__ int   se[2];
  const int t = threadIdx.x;
  const int b = blockIdx.x;

  ((f32x4*)qs)[t] = ((const f32x4*)(q + (size_t)b * H_))[t];
  __syncthreads();

  {
    const int jq = t & 127, ih = t >> 7;
    f32x4 acc = {0.f, 0.f, 0.f, 0.f};
    const float* wp = w1 + (size_t)(ih * 512) * HID_ + 4 * jq;
    for (int i = 0; i < 512; ++i) {
      acc += qs[ih * 512 + i] * *(const f32x4*)(wp + (size_t)i * HID_);
    }
    *(f32x4*)&red[t][0] = acc;
  }
  __syncthreads();
  if (t < 128) {
    f32x4 a = *(f32x4*)&red[t][0];
    a += *(f32x4*)&red[t + 128][0];
    a += *(const f32x4*)(b1 + 4 * t);
    f32x4 r;
    #pragma unroll
    for (int c = 0; c < 4; ++c) r[c] = fmaxf(a[c], 0.f);
    *(f32x4*)&hid[4 * t] = r;
  }
  __syncthreads();

  {
    const float h0 = hid[t], h1 = hid[t + 256];
    const float* w2a = w2 + (size_t)t * E_;
    const float* w2b = w2 + (size_t)(t + 256) * E_;
    #pragma unroll
    for (int e = 0; e < 8; ++e) red[t][e] = h0 * w2a[e] + h1 * w2b[e];
  }
  __syncthreads();
  for (int s = 128; s > 0; s >>= 1) {
    if (t < s) {
      #pragma unroll
      for (int e = 0; e < 8; ++e) red[t][e] += red[t + s][e];
    }
    __syncthreads();
  }

  if (t == 0) {
    float lg[8];
    #pragma unroll
    for (int e = 0; e < 8; ++e) lg[e] = red[0][e] + b2[e];
    int e1 = 0;
    #pragma unroll
    for (int e = 1; e < 8; ++e) if (lg[e] > lg[e1]) e1 = e;     // lowest idx wins ties
    int e2 = (e1 == 0) ? 1 : 0;
    #pragma unroll
    for (int e = 0; e < 8; ++e) if (e != e1 && lg[e] > lg[e2]) e2 = e;
    const float x2 = expf(lg[e2] - lg[e1]);
    const float g1 = 1.f / (1.f + x2);
    const float g2 = x2 / (1.f + x2);
    #pragma unroll
    for (int e = 0; e < 8; ++e)
      gates[b * E_ + e] = (e == e1) ? g1 : (e == e2) ? g2 : 0.f;
    egate[2 * b] = g1; egate[2 * b + 1] = g2;
    eidx[2 * b]  = e1; eidx[2 * b + 1]  = e2;
    sg[0] = g1; sg[1] = g2; se[0] = e1; se[1] = e2;
  }
  __syncthreads();

  {
    const float gg1 = sg[0], gg2 = sg[1];
    const int ee1 = se[0], ee2 = se[1];
    const int o = t >> 4, sub = t & 15;
    const float* hl = h  + ((size_t)(b * L_ + (L_ - 1))) * H_ + sub * 64;
    const float* wa = gw + ((size_t)(ee1 * OUT_ + o)) * H_ + sub * 64;
    const float* wb = gw + ((size_t)(ee2 * OUT_ + o)) * H_ + sub * 64;
    float p = 0.f;
    #pragma unroll 4
    for (int i = 0; i < 64; i += 4) {
      const f32x4 hv = *(const f32x4*)(hl + i);
      const f32x4 va = *(const f32x4*)(wa + i);
      const f32x4 vb = *(const f32x4*)(wb + i);
      const f32x4 w  = gg1 * va + gg2 * vb;
      p += hv[0] * w[0] + hv[1] * w[1] + hv[2] * w[2] + hv[3] * w[3];
    }
    float* red1 = &red[0][0];
    red1[t] = p;
    __syncthreads();
    if (t < 16) {
      float s = gg1 * gb[ee1 * OUT_ + t] + gg2 * gb[ee2 * OUT_ + t];
      #pragma unroll
      for (int k2 = 0; k2 < 16; ++k2) s += red1[t * 16 + k2];
      out[b * OUT_ + t] = 1.f / (1.f + expf(-s));
    }
  }
}

// ---------------------------------------------------------------------------
// Kernel: moe_loss only.
// ---------------------------------------------------------------------------
__global__ __launch_bounds__(64) void k_loss(const float* __restrict__ gates,
                                             float* __restrict__ out) {
  __shared__ float imp[8];
  const int t = threadIdx.x;
  if (t < 8) {
    float s = 0.f;
    for (int b = 0; b < B_; ++b) s += gates[b * E_ + t];
    imp[t] = s;
  }
  __syncthreads();
  if (t == 0) {
    float m = 0.f;
    #pragma unroll
    for (int e = 0; e < 8; ++e) m += imp[e];
    m *= 0.125f;
    float var = 0.f;
    #pragma unroll
    for (int e = 0; e < 8; ++e) { const float d = imp[e] - m; var += d * d; }
    var *= (1.f / 7.f);
    out[LOSS_OFF] = sqrtf(var) / (m + 1e-10f) * 0.1f;
  }
}

// ---------------------------------------------------------------------------
// Kernel 3 (fast): comp GEMM, fused f32->bf16 mix, XCD-confined vt mapping.
// EXACT round-3 structure (302 us) with ONE change: the post-MFMA barrier is
// a raw s_barrier (no vmcnt/lgkmcnt drain). Rationale:
//   - sync1 (after WRITEB, __syncthreads): drains GLOAD(u)+LOADB stragglers.
//     Those were issued a FULL iteration earlier -> drain is cheap, and it is
//     exactly what MFMA(u) needs (A tile complete).
//   - sync2 (after MFMA, raw): protects only Bs WAR / As[(u+1)&1] WAR, both
//     satisfied by barrier semantics alone (all ds_reads retire before their
//     consuming MFMAs, which precede barrier arrival). The old vmcnt(0) here
//     drained tile-(u+1) loads with only ~12 MFMAs of cover -> THE stall.
// No asm fences, no forced unroll: compiler keeps scheduling freedom
// (round-4 lesson: pinning the scheduler regressed 302->356).
// ---------------------------------------------------------------------------
__global__ __launch_bounds__(256) void k_comp_fast(
    const short* __restrict__ hbf, const float* __restrict__ cw,
    const float* __restrict__ cb,  const float* __restrict__ egate,
    const int* __restrict__ eidx,  float* __restrict__ out) {
  __shared__ __align__(16) short As[2][64 * 64];   // 2 x 8 KB (double-buffered)
  __shared__ __align__(16) short Bs[96 * 64];      // 12 KB (mixed weights)
  const int t  = threadIdx.x;
  const int id  = blockIdx.x;
  const int xcd = id & 7;
  const int pos = id >> 3;          // 0..511
  const int b   = pos & 31;
  const int g   = pos >> 5;         // 0..15
  const int vt  = g * 8 + xcd;      // 0..127
  if (vt >= NVT) return;            // 125 valid tiles; 96 idle blocks exit
  const int e1 = eidx[2 * b], e2 = eidx[2 * b + 1];
  const float g1 = egate[2 * b], g2 = egate[2 * b + 1];

  // --- A staging: GLOAD16, linear LDS dest, inverse-swizzled global source ---
  const int srow = t >> 3, schunk = t & 7;
  const unsigned soff = (unsigned)((schunk << 4) ^ ((srow & 7) << 4));
  const char* sAk = (const char*)hbf + ((size_t)b * 64 + srow) * 2048 + soff;
  char* dA0 = (char*)&As[0][0] + t * 16;
  char* dA1 = (char*)&As[1][0] + t * 16;

  // --- B staging: 3 passes x 32 rows; row = p*32 + srow, cols schunk*8..+8 ---
  const float* wB1 = cw + ((size_t)e1 * V_ + (size_t)vt * BN + srow) * H_ + schunk * 8;
  const float* wB2 = cw + ((size_t)e2 * V_ + (size_t)vt * BN + srow) * H_ + schunk * 8;
  short* dBp = Bs + srow * 64 + ((schunk ^ (srow & 7)) << 3);   // swizzled write base

  f32x4 r1[3][2], r2[3][2];   // both experts' f32 rows for one k-tile

#define LOADB(koff)                                                          \
  do {                                                                       \
    _Pragma("unroll")                                                        \
    for (int p = 0; p < 3; ++p) {                                            \
      r1[p][0] = *(const f32x4*)(wB1 + (size_t)p * 32 * H_ + (koff));        \
      r1[p][1] = *(const f32x4*)(wB1 + (size_t)p * 32 * H_ + (koff) + 4);    \
      r2[p][0] = *(const f32x4*)(wB2 + (size_t)p * 32 * H_ + (koff));        \
      r2[p][1] = *(const f32x4*)(wB2 + (size_t)p * 32 * H_ + (koff) + 4);    \
    }                                                                        \
  } while (0)

#define WRITEB()                                                             \
  do {                                                                       \
    _Pragma("unroll")                                                        \
    for (int p = 0; p < 3; ++p) {                                            \
      const f32x4 m0 = g1 * r1[p][0] + g2 * r2[p][0];                        \
      const f32x4 m1 = g1 * r1[p][1] + g2 * r2[p][1];                        \
      bf16x8 o;                                                              \
      o[0] = f2bf(m0[0]); o[1] = f2bf(m0[1]);                                \
      o[2] = f2bf(m0[2]); o[3] = f2bf(m0[3]);                                \
      o[4] = f2bf(m1[0]); o[5] = f2bf(m1[1]);                                \
      o[6] = f2bf(m1[2]); o[7] = f2bf(m1[3]);                                \
      *(bf16x8*)(dBp + p * 32 * 64) = o;                                     \
    }                                                                        \
  } while (0)

  // --- mfma geometry (wave: mh = M-half of 32 rows, ng*3..+3 = N-frags) ---
  const int lane = t & 63, wv = t >> 6;
  const int lr = lane & 15, quad = lane >> 4;
  const int mh = wv & 1, ng = wv >> 1;
  int offA[2][2], offB[3][2];   // [frag][ks] in shorts
  #pragma unroll
  for (int mf = 0; mf < 2; ++mf) {
    const int ra = mh * 32 + mf * 16 + lr;
    offA[mf][0] = ra * 64 + (((quad    ) ^ (ra & 7)) << 3);
    offA[mf][1] = ra * 64 + (((quad ^ 4) ^ (ra & 7)) << 3);
  }
  #pragma unroll
  for (int nn = 0; nn < 3; ++nn) {
    const int rb = (ng * 3 + nn) * 16 + lr;
    offB[nn][0] = rb * 64 + (((quad    ) ^ (rb & 7)) << 3);
    offB[nn][1] = rb * 64 + (((quad ^ 4) ^ (rb & 7)) << 3);
  }

  f32x4 acc[2][3];
  #pragma unroll
  for (int i = 0; i < 2; ++i)
    #pragma unroll
    for (int j = 0; j < 3; ++j) acc[i][j] = (f32x4){0.f, 0.f, 0.f, 0.f};

  // prologue: tile 0 in flight
  GLOAD16(sAk,         dA0);
  GLOAD16(sAk + 65536, dA0 + 4096);
  sAk += 128;
  LOADB(0);
  int koff = 64;

  for (int t16 = 0; t16 < 16; ++t16) {
    // phase 1: commit tile t's mixed B to LDS (regs loaded a full phase ago)
    WRITEB();
    __syncthreads();   // drains tile t's A GLOADs (issued one phase earlier)

    // phase 2: issue tile t+1's loads, then compute tile t
    if (t16 < 15) {
      char* dAn = (t16 & 1) ? dA0 : dA1;   // next buffer = (t16+1)&1
      GLOAD16(sAk,         dAn);
      GLOAD16(sAk + 65536, dAn + 4096);
      sAk += 128;
      LOADB(koff);
      koff += 64;
    }
    const short* Asb = &As[t16 & 1][0];
    #pragma unroll
    for (int ks = 0; ks < 2; ++ks) {
      const bf16x8 a0 = *(const bf16x8*)(Asb + offA[0][ks]);
      const bf16x8 a1 = *(const bf16x8*)(Asb + offA[1][ks]);
      #pragma unroll
      for (int nn = 0; nn < 3; ++nn) {
        const bf16x8 wbm = *(const bf16x8*)(Bs + offB[nn][ks]);
        acc[0][nn] = __builtin_amdgcn_mfma_f32_16x16x32_bf16(a0, wbm, acc[0][nn], 0, 0, 0);
        acc[1][nn] = __builtin_amdgcn_mfma_f32_16x16x32_bf16(a1, wbm, acc[1][nn], 0, 0, 0);
      }
    }
    // raw barrier: Bs/As WAR only — tile-(t+1) loads stay in flight
    __builtin_amdgcn_s_barrier();
  }

  // epilogue: mixed bias (D layout: col=lane&15, row=quad*4+r)
  #pragma unroll
  for (int nn = 0; nn < 3; ++nn) {
    const int v = vt * BN + (ng * 3 + nn) * 16 + lr;
    const float bias = g1 * cb[e1 * V_ + v] + g2 * cb[e2 * V_ + v];
    #pragma unroll
    for (int mf = 0; mf < 2; ++mf) {
      const int lbase = mh * 32 + mf * 16 + quad * 4;
      float* op = out + COMP_OFF + ((size_t)(b * L_ + lbase)) * V_ + v;
      #pragma unroll
      for (int rr = 0; rr < 4; ++rr)
        op[(size_t)rr * V_] = acc[mf][nn][rr] + bias;
    }
  }
#undef LOADB
#undef WRITEB
}

// ---------------------------------------------------------------------------
// Kernel 3 (fallback, tiny-workspace path): f32 direct, mix-in-staging.
// ---------------------------------------------------------------------------
__global__ __launch_bounds__(256) void k_comp(
    const float* __restrict__ h,     const float* __restrict__ cw,
    const float* __restrict__ cbp,   const float* __restrict__ egate,
    const int* __restrict__ eidx,    float* __restrict__ out) {
  __shared__ __align__(16) short As[L_ * LDK];
  __shared__ __align__(16) short Bs[BN * LDK];
  const int t  = threadIdx.x;
  const int b  = blockIdx.x;
  const int vt = blockIdx.y;
  const int e1 = eidx[2 * b], e2 = eidx[2 * b + 1];
  const float g1 = egate[2 * b], g2 = egate[2 * b + 1];

  const float* hrow = h + ((size_t)b * L_ + (t >> 2)) * H_ + ((t & 3) * 16);
  const float* w1p  = cw + ((size_t)e1 * V_ + (size_t)vt * BN) * H_;
  const float* w2p  = cw + ((size_t)e2 * V_ + (size_t)vt * BN) * H_;

  f32x4 acc[6];
  #pragma unroll
  for (int i = 0; i < 6; ++i) acc[i] = (f32x4){0.f, 0.f, 0.f, 0.f};

  const int wv = t >> 6;
  const int lane = t & 63;
  const int lr = lane & 15, quad = lane >> 4;
  const short* Ap = As + (wv * 16 + lr) * LDK;
  const short* Bp = Bs + lr * LDK;

  const int wr = t >> 3;
  const int wc = (t & 7) * 8;

  for (int k0 = 0; k0 < H_; k0 += BK) {
    {
      const float* src = hrow + k0;
      short* dst = As + (t >> 2) * LDK + (t & 3) * 16;
      #pragma unroll
      for (int c = 0; c < 16; c += 4) {
        const f32x4 v = *(const f32x4*)(src + c);
        s16x4 sv;
        sv[0] = f2bf(v[0]); sv[1] = f2bf(v[1]);
        sv[2] = f2bf(v[2]); sv[3] = f2bf(v[3]);
        *(s16x4*)(dst + c) = sv;
      }
    }
    #pragma unroll
    for (int p = 0; p < 3; ++p) {
      const int r = p * 32 + wr;
      const float* s1 = w1p + (size_t)r * H_ + k0 + wc;
      const float* s2 = w2p + (size_t)r * H_ + k0 + wc;
      short* dst = Bs + r * LDK + wc;
      #pragma unroll
      for (int c = 0; c < 8; c += 4) {
        const f32x4 a  = *(const f32x4*)(s1 + c);
        const f32x4 bb = *(const f32x4*)(s2 + c);
        const f32x4 m  = g1 * a + g2 * bb;
        s16x4 sv;
        sv[0] = f2bf(m[0]); sv[1] = f2bf(m[1]);
        sv[2] = f2bf(m[2]); sv[3] = f2bf(m[3]);
        *(s16x4*)(dst + c) = sv;
      }
    }
    __syncthreads();

    #pragma unroll
    for (int ks = 0; ks < BK; ks += 32) {
      const bf16x8 af = *(const bf16x8*)(Ap + ks + quad * 8);
      #pragma unroll
      for (int n = 0; n < 6; ++n) {
        const bf16x8 bf = *(const bf16x8*)(Bp + n * 16 * LDK + ks + quad * 8);
        acc[n] = __builtin_amdgcn_mfma_f32_16x16x32_bf16(af, bf, acc[n], 0, 0, 0);
      }
    }
    __syncthreads();
  }

  #pragma unroll
  for (int n = 0; n < 6; ++n) {
    const int v = vt * BN + n * 16 + lr;
    const float bias = g1 * cbp[e1 * V_ + v] + g2 * cbp[e2 * V_ + v];
    #pragma unroll
    for (int r = 0; r < 4; ++r) {
      const int l = wv * 16 + quad * 4 + r;
      out[COMP_OFF + ((size_t)(b * L_ + l)) * V_ + v] = acc[n][r] + bias;
    }
  }
}

// ---------------------------------------------------------------------------
extern "C" void kernel_launch(void* const* d_in, const int* in_sizes, int n_in,
                              void* d_out, int out_size, void* d_ws, size_t ws_size,
                              hipStream_t stream) {
  const float* q   = (const float*)d_in[0];
  const float* h   = (const float*)d_in[1];
  const float* w1  = (const float*)d_in[2];
  const float* b1  = (const float*)d_in[3];
  const float* w2  = (const float*)d_in[4];
  const float* b2  = (const float*)d_in[5];
  const float* gw  = (const float*)d_in[6];
  const float* gb  = (const float*)d_in[7];
  const float* cw  = (const float*)d_in[8];
  const float* cbp = (const float*)d_in[9];
  float* out = (float*)d_out;

  // ws layout: [0,1024) gates/egate/eidx block; [4096, +4MB) h_bf16.
  float* F     = (float*)d_ws;
  float* gates = F;
  float* egate = F + 256;
  int*   eidx  = (int*)(F + 320);

  const size_t HBF_OFF = 4096;
  const size_t HBF_BYTES = (size_t)B_ * L_ * H_ * 2;   // 4,194,304
  const size_t WS_NEED = HBF_OFF + HBF_BYTES;

  k_gate<<<B_, 256, 0, stream>>>(q, w1, b1, w2, b2, h, gw, gb, gates, egate, eidx, out);
  k_loss<<<1, 64, 0, stream>>>(gates, out);

  if (ws_size >= WS_NEED) {
    short* hbf = (short*)((char*)d_ws + HBF_OFF);
    k_conv<<<256, 256, 0, stream>>>(h, hbf, (int)((size_t)B_ * L_ * H_ / 8));
    // 4096 blocks: 512 per XCD under id%8 round-robin; 96 exit early (vt>=125)
    k_comp_fast<<<4096, 256, 0, stream>>>(hbf, cw, cbp, egate, eidx, out);
  } else {
    k_comp<<<dim3(B_, V_ / BN), 256, 0, stream>>>(h, cw, cbp, egate, eidx, out);
  }
}